// Round 6
// baseline (709.793 us; speedup 1.0000x reference)
//
#include <hip/hip_runtime.h>

// N=8192, DIN=DH=DOUT=64, SPARSITY=0.01 -> ~82 nnz/row
// (row nnz ~ Binom(8192,0.01): mean 82, std 9; CAP=256 = 19 sigma)
#define NN   8192
#define DD   64
#define CAP  256
#define GRID 512    // 2 blocks/CU x 256 CU; launch_bounds(256,2) guarantees
                    // co-residency (LDS 25.9KB -> 6/CU; VGPR<=256 -> 2/CU)

struct Shm {
    union {
        struct {                    // scan + layer-1 phase
            int    scols[CAP];
            float  svals[CAP];
            float4 sagg2[16][16];   // [group][dim-chunk]
        } s;
        struct {                    // layer-2/3 phase
            float  WT[DD * 65];     // stride-65: conflict-free transposed W
            int2   spairs[4][CAP];  // wave-private slabs
            float4 sagg[4][16];
        } l;
    };
    int scnt;
};

// One-shot software grid barrier (counter not reused -> no sense reversal).
// Writer: device-scope fence then arrive. Reader: agent-scope atomic spin,
// then fence so subsequent normal loads don't hit stale L1/L2.
__device__ __forceinline__ void grid_barrier(int* bar)
{
    __syncthreads();
    if (threadIdx.x == 0) {
        __threadfence();                         // release prior global writes
        atomicAdd(bar, 1);                       // device-scope arrive
        while (__hip_atomic_load(bar, __ATOMIC_RELAXED,
                                 __HIP_MEMORY_SCOPE_AGENT) < GRID)
            __builtin_amdgcn_s_sleep(1);
    }
    __syncthreads();
    __threadfence();                             // acquire for all waves
}

// Layer pass: 4 rows per block per rg-iteration (wave = row), grid-stride.
// Logic identical to the R1/R4-verified layer_kernel.
__device__ __forceinline__ void layer_pass(
    Shm& sh, const float* __restrict__ xin, float* __restrict__ xout,
    const float* __restrict__ W, const float* __restrict__ bias,
    const int2* __restrict__ pairs, const int* __restrict__ cnt)
{
    const int tid  = threadIdx.x;
    const int wave = tid >> 6;
    const int lane = tid & 63;
    const int grp  = lane >> 4;
    const int l16  = lane & 15;

    for (int i = tid; i < DD * DD; i += 256)
        sh.l.WT[(i & 63) * 65 + (i >> 6)] = W[i];
    __syncthreads();

    const float4* x4 = (const float4*)xin;

    for (int rg = blockIdx.x; rg < NN / 4; rg += GRID) {
        const int r = rg * 4 + wave;
        const int n = cnt[r];
        const int nr = (n + 15) & ~15;
        const size_t base = (size_t)r * CAP;

        for (int j = lane; j < n; j += 64)      sh.l.spairs[wave][j] = pairs[base + j];
        for (int j = n + lane; j < nr; j += 64) sh.l.spairs[wave][j] = make_int2(0, 0);
        __syncthreads();

        float4 agg = make_float4(0.f, 0.f, 0.f, 0.f);
        for (int j0 = grp * 4; j0 < nr; j0 += 16) {
            int2 cv[4];
            #pragma unroll
            for (int t = 0; t < 4; ++t) cv[t] = sh.l.spairs[wave][j0 + t];
            float4 xv[4];
            #pragma unroll
            for (int t = 0; t < 4; ++t)
                xv[t] = x4[(size_t)cv[t].x * (DD / 4) + l16];  // 4 gathers in flight
            #pragma unroll
            for (int t = 0; t < 4; ++t) {
                const float v = __int_as_float(cv[t].y);
                agg.x += v * xv[t].x; agg.y += v * xv[t].y;
                agg.z += v * xv[t].z; agg.w += v * xv[t].w;
            }
        }
        agg.x += __shfl_xor(agg.x, 16); agg.y += __shfl_xor(agg.y, 16);
        agg.z += __shfl_xor(agg.z, 16); agg.w += __shfl_xor(agg.w, 16);
        agg.x += __shfl_xor(agg.x, 32); agg.y += __shfl_xor(agg.y, 32);
        agg.z += __shfl_xor(agg.z, 32); agg.w += __shfl_xor(agg.w, 32);
        if (grp == 0) sh.l.sagg[wave][l16] = agg;
        __syncthreads();

        const float* sa = (const float*)&sh.l.sagg[wave][0];
        float acc = bias[lane];
        #pragma unroll 16
        for (int k = 0; k < DD; ++k)
            acc += sa[k] * sh.l.WT[k * 65 + lane];
        xout[(size_t)r * DD + lane] = acc;
        // next-iter spairs writes are ordered after this read by the
        // __syncthreads at the top of the next iteration's gather
    }
}

// Single regular dispatch (graph-capturable), persistent blocks:
//   Phase 1 (grid-stride rows): A-stream scan + compaction + deferred lw
//            gather + slab write + fused layer-1 from the LDS slab.
//   software grid barrier -> layer-2 -> barrier -> layer-3.
__global__ __launch_bounds__(256, 2) void fused_kernel(
    const float* __restrict__ x, const float* __restrict__ A,
    const float* __restrict__ lw,
    const float* __restrict__ W0, const float* __restrict__ b0,
    const float* __restrict__ W1, const float* __restrict__ b1,
    const float* __restrict__ W2, const float* __restrict__ b2,
    int2* __restrict__ pairs, int* __restrict__ cnt,
    float* __restrict__ bufA, float* __restrict__ bufB,
    float* __restrict__ out, int* bar)
{
    __shared__ Shm sh;
    const int tid = threadIdx.x;

    // ---- Phase 1: scan + layer-1 (one block per row, grid-stride) ----
    for (int r = blockIdx.x; r < NN; r += GRID) {
        if (tid == 0) sh.scnt = 0;
        __syncthreads();

        const float4* A4 = (const float4*)(A + (size_t)r * NN);
        float4 a[8];
        #pragma unroll
        for (int k = 0; k < 8; ++k) a[k] = A4[tid + 256 * k];

        #pragma unroll
        for (int k = 0; k < 8; ++k) {
            const bool nzk = (a[k].x != 0.f) || (a[k].y != 0.f) ||
                             (a[k].z != 0.f) || (a[k].w != 0.f);
            if (nzk) {                       // ~27% of threads; exec-masked
                const int cbase = 4 * (tid + 256 * k);
                #define EMIT(comp, off)                                     \
                    if (a[k].comp != 0.f) {                                 \
                        int p = atomicAdd(&sh.scnt, 1);                     \
                        if (p < CAP) sh.s.scols[p] = cbase + off;           \
                    }
                EMIT(x, 0) EMIT(y, 1) EMIT(z, 2) EMIT(w, 3)
                #undef EMIT
            }
        }
        __syncthreads();

        int n = sh.scnt; if (n > CAP) n = CAP;
        int nr = (n + 15) & ~15; if (nr == 0) nr = 16;
        if (tid == 0) cnt[r] = n;
        if (tid < n) {                       // deferred lw gather + slab write
            const int c = sh.s.scols[tid];
            const float v = lw[(size_t)r * NN + c];
            sh.s.svals[tid] = v;
            pairs[(size_t)r * CAP + tid] = make_int2(c, __float_as_int(v));
        } else if (tid < nr) {               // zero-pad to x16
            sh.s.scols[tid] = 0;
            sh.s.svals[tid] = 0.f;
        }
        __syncthreads();

        // layer-1 aggregation from the LDS slab (16 groups x 16 dim-chunks)
        const int g   = tid >> 4;
        const int l16 = tid & 15;
        const float4* x4 = (const float4*)x;

        float4 agg = make_float4(0.f, 0.f, 0.f, 0.f);
        for (int j = g; j < nr; j += 16) {
            const int   c = sh.s.scols[j];
            const float v = sh.s.svals[j];
            const float4 xv = x4[(size_t)c * (DD / 4) + l16];
            agg.x += v * xv.x; agg.y += v * xv.y;
            agg.z += v * xv.z; agg.w += v * xv.w;
        }
        sh.s.sagg2[g][l16] = agg;
        __syncthreads();

        #pragma unroll
        for (int s = 8; s >= 1; s >>= 1) {
            if (g < s) {
                float4 o = sh.s.sagg2[g + s][l16];
                float4 m = sh.s.sagg2[g][l16];
                m.x += o.x; m.y += o.y; m.z += o.z; m.w += o.w;
                sh.s.sagg2[g][l16] = m;
            }
            __syncthreads();
        }

        if (tid < DD) {
            const float* sa = (const float*)&sh.s.sagg2[0][0];
            float acc = b0[tid];
            const float4* w4 = (const float4*)(W0 + (size_t)tid * DD);
            #pragma unroll
            for (int k4 = 0; k4 < 16; ++k4) {
                const float4 wv = w4[k4];
                acc += sa[4 * k4 + 0] * wv.x + sa[4 * k4 + 1] * wv.y
                     + sa[4 * k4 + 2] * wv.z + sa[4 * k4 + 3] * wv.w;
            }
            bufA[(size_t)r * DD + tid] = acc;
        }
        __syncthreads();                     // protect scnt/scols/svals WAR
    }

    grid_barrier(bar + 0);                   // publish bufA/pairs/cnt across XCDs
    layer_pass(sh, bufA, bufB, W1, b1, pairs, cnt);
    grid_barrier(bar + 1);                   // publish bufB
    layer_pass(sh, bufB, out,  W2, b2, pairs, cnt);
}

extern "C" void kernel_launch(void* const* d_in, const int* in_sizes, int n_in,
                              void* d_out, int out_size, void* d_ws, size_t ws_size,
                              hipStream_t stream) {
    const float* x  = (const float*)d_in[0];
    const float* A  = (const float*)d_in[1];
    const float* lw = (const float*)d_in[2];
    const float* W0 = (const float*)d_in[3];
    const float* b0 = (const float*)d_in[4];
    const float* W1 = (const float*)d_in[5];
    const float* b1 = (const float*)d_in[6];
    const float* W2 = (const float*)d_in[7];
    const float* b2 = (const float*)d_in[8];
    float* out = (float*)d_out;

    char* ws = (char*)d_ws;
    int2*  pairs = (int2*)ws;  ws += (size_t)NN * CAP * sizeof(int2);  // 16 MB
    int*   cnt   = (int*)ws;   ws += (size_t)NN * sizeof(int);
    float* bufA  = (float*)ws; ws += (size_t)NN * DD * sizeof(float);
    float* bufB  = (float*)ws; ws += (size_t)NN * DD * sizeof(float);
    int*   bar   = (int*)ws;

    // workspace is poisoned each iteration: barrier counters must be zeroed
    // (hipMemsetAsync is graph-capturable; harness uses it itself)
    hipMemsetAsync(bar, 0, 2 * sizeof(int), stream);

    fused_kernel<<<GRID, 256, 0, stream>>>(
        x, A, lw, W0, b0, W1, b1, W2, b2,
        pairs, cnt, bufA, bufB, out, bar);
}

// Round 8
// 597.633 us; speedup vs baseline: 1.1877x; 1.1877x over previous
//
#include <hip/hip_runtime.h>

// N=8192, DIN=DH=DOUT=64, SPARSITY=0.01 -> ~82 nnz/row
// (row nnz ~ Binom(8192,0.01): mean 82, std 9; CAP=256 = 19 sigma)
#define NN  8192
#define DD  64
#define CAP 256

// ---------------------------------------------------------------------------
// S1 "detect": pure copy-shaped stream of A. 2048 blocks x 256 threads,
// grid-stride over the flat float4 array (32 float4/thread, 2 in flight).
// No LDS, no syncthreads, no per-row block lifetime -- the only deviation
// from a straight read-stream is the rare (4% of threads) emission of
// column indices via one device-scope atomic per nonzero.
// ---------------------------------------------------------------------------
#define DET_BLOCKS 2048
#define DET_NT     (DET_BLOCKS * 256)            // 524288 threads
#define DET_TOTAL  (NN * (NN / 4))               // 16777216 float4
#define DET_ITERS  (DET_TOTAL / DET_NT)          // 32

__device__ __forceinline__ void det_emit(
    float4 v, int f, int* __restrict__ cnt, int* __restrict__ colbuf)
{
    const bool any = (v.x != 0.f) || (v.y != 0.f) || (v.z != 0.f) || (v.w != 0.f);
    if (any) {                                   // ~4% of threads; exec-masked
        const int row = f >> 11;                 // f / (NN/4)
        const int cb  = (f & 2047) << 2;         // 4*(f % (NN/4))
        #define DEMIT(comp, off)                                            \
            if (v.comp != 0.f) {                                            \
                int s = atomicAdd(&cnt[row], 1);                            \
                if (s < CAP) colbuf[(size_t)row * CAP + s] = cb + off;      \
            }
        DEMIT(x, 0) DEMIT(y, 1) DEMIT(z, 2) DEMIT(w, 3)
        #undef DEMIT
    }
}

__global__ __launch_bounds__(256) void detect_kernel(
    const float* __restrict__ A, int* __restrict__ cnt, int* __restrict__ colbuf)
{
    const float4* A4 = (const float4*)A;
    int idx = blockIdx.x * 256 + threadIdx.x;
    #pragma unroll 1
    for (int it = 0; it < DET_ITERS; it += 2) {  // 2 loads in flight / thread
        const float4 v0 = A4[idx];
        const float4 v1 = A4[idx + DET_NT];
        det_emit(v0, idx,          cnt, colbuf);
        det_emit(v1, idx + DET_NT, cnt, colbuf);
        idx += 2 * DET_NT;
    }
}

// ---------------------------------------------------------------------------
// L1: one block per row. Stage cols from colbuf, gather lw values (and
// materialize the int2 pairs slab for layers 2/3), then the R4-verified
// phase-B aggregation + 64x64 linear.
// ---------------------------------------------------------------------------
__global__ __launch_bounds__(256) void l1_kernel(
    const float* __restrict__ lw, const float* __restrict__ x,
    const float* __restrict__ W0, const float* __restrict__ b0,
    const int* __restrict__ cnt, const int* __restrict__ colbuf,
    int2* __restrict__ pairs, float* __restrict__ bufA)
{
    __shared__ int    scols[CAP];
    __shared__ float  svals[CAP];
    __shared__ float4 sagg2[16][16];   // [group][dim-chunk]

    const int tid = threadIdx.x;
    const int r   = blockIdx.x;

    int n = cnt[r]; if (n > CAP) n = CAP;
    int nr = (n + 15) & ~15; if (nr == 0) nr = 16;

    if (tid < n) {                     // coalesced col read + scattered lw gather
        const int   c = colbuf[(size_t)r * CAP + tid];
        const float v = lw[(size_t)r * NN + c];
        scols[tid] = c;
        svals[tid] = v;
        pairs[(size_t)r * CAP + tid] = make_int2(c, __float_as_int(v));
    } else if (tid < nr) {             // zero-pad to x16
        scols[tid] = 0;
        svals[tid] = 0.f;
    }
    __syncthreads();

    // phase B: aggregation from LDS slab (16 groups x 16 dim-chunks) [R4-verified]
    const int g   = tid >> 4;
    const int l16 = tid & 15;
    const float4* x4 = (const float4*)x;

    float4 agg = make_float4(0.f, 0.f, 0.f, 0.f);
    for (int j = g; j < nr; j += 16) {
        const int   c = scols[j];
        const float v = svals[j];
        const float4 xv = x4[(size_t)c * (DD / 4) + l16];
        agg.x += v * xv.x; agg.y += v * xv.y;
        agg.z += v * xv.z; agg.w += v * xv.w;
    }
    sagg2[g][l16] = agg;
    __syncthreads();

    #pragma unroll
    for (int s = 8; s >= 1; s >>= 1) {
        if (g < s) {
            float4 o = sagg2[g + s][l16];
            float4 m = sagg2[g][l16];
            m.x += o.x; m.y += o.y; m.z += o.z; m.w += o.w;
            sagg2[g][l16] = m;
        }
        __syncthreads();
    }

    if (tid < DD) {
        const float* sa = (const float*)&sagg2[0][0];
        float acc = b0[tid];
        const float4* w4 = (const float4*)(W0 + (size_t)tid * DD);
        #pragma unroll
        for (int k4 = 0; k4 < 16; ++k4) {
            const float4 wv = w4[k4];
            acc += sa[4 * k4 + 0] * wv.x + sa[4 * k4 + 1] * wv.y
                 + sa[4 * k4 + 2] * wv.z + sa[4 * k4 + 3] * wv.w;
        }
        bufA[(size_t)r * DD + tid] = acc;
    }
}

// Layer pass (x2): 4 rows per 256-thread block, wave = row. R1/R4-verified.
__global__ __launch_bounds__(256) void layer_kernel(
    const float* __restrict__ xin,
    const int2* __restrict__ pairs, const int* __restrict__ cnt,
    const float* __restrict__ W, const float* __restrict__ bias,
    float* __restrict__ xout)
{
    __shared__ float  WT[DD * 65];
    __shared__ int2   spairs[4][CAP];
    __shared__ float4 sagg[4][16];

    const int tid  = threadIdx.x;
    const int wave = tid >> 6;
    const int lane = tid & 63;
    const int grp  = lane >> 4;
    const int l16  = lane & 15;

    for (int i = tid; i < DD * DD; i += 256)
        WT[(i & 63) * 65 + (i >> 6)] = W[i];   // stride-65: conflict-free

    const int r  = blockIdx.x * 4 + wave;
    int n = cnt[r]; if (n > CAP) n = CAP;
    const int nr = (n + 15) & ~15;
    const size_t base = (size_t)r * CAP;

    for (int j = lane; j < n; j += 64)      spairs[wave][j] = pairs[base + j];
    for (int j = n + lane; j < nr; j += 64) spairs[wave][j] = make_int2(0, 0);
    __syncthreads();

    const float4* x4 = (const float4*)xin;
    float4 agg = make_float4(0.f, 0.f, 0.f, 0.f);
    for (int j0 = grp * 4; j0 < nr; j0 += 16) {
        int2 cv[4];
        #pragma unroll
        for (int t = 0; t < 4; ++t) cv[t] = spairs[wave][j0 + t];
        float4 xv[4];
        #pragma unroll
        for (int t = 0; t < 4; ++t)
            xv[t] = x4[(size_t)cv[t].x * (DD / 4) + l16];  // 4 gathers in flight
        #pragma unroll
        for (int t = 0; t < 4; ++t) {
            const float v = __int_as_float(cv[t].y);
            agg.x += v * xv[t].x; agg.y += v * xv[t].y;
            agg.z += v * xv[t].z; agg.w += v * xv[t].w;
        }
    }
    agg.x += __shfl_xor(agg.x, 16); agg.y += __shfl_xor(agg.y, 16);
    agg.z += __shfl_xor(agg.z, 16); agg.w += __shfl_xor(agg.w, 16);
    agg.x += __shfl_xor(agg.x, 32); agg.y += __shfl_xor(agg.y, 32);
    agg.z += __shfl_xor(agg.z, 32); agg.w += __shfl_xor(agg.w, 32);
    if (grp == 0) sagg[wave][l16] = agg;
    __syncthreads();

    const float* sa = (const float*)&sagg[wave][0];
    float acc = bias[lane];
    #pragma unroll 16
    for (int k = 0; k < DD; ++k)
        acc += sa[k] * WT[k * 65 + lane];
    xout[(size_t)r * DD + lane] = acc;
}

extern "C" void kernel_launch(void* const* d_in, const int* in_sizes, int n_in,
                              void* d_out, int out_size, void* d_ws, size_t ws_size,
                              hipStream_t stream) {
    const float* x  = (const float*)d_in[0];
    const float* A  = (const float*)d_in[1];
    const float* lw = (const float*)d_in[2];
    const float* W0 = (const float*)d_in[3];
    const float* b0 = (const float*)d_in[4];
    const float* W1 = (const float*)d_in[5];
    const float* b1 = (const float*)d_in[6];
    const float* W2 = (const float*)d_in[7];
    const float* b2 = (const float*)d_in[8];
    float* out = (float*)d_out;

    char* ws = (char*)d_ws;
    int2*  pairs  = (int2*)ws; ws += (size_t)NN * CAP * sizeof(int2);  // 16 MB
    int*   colbuf = (int*)ws;  ws += (size_t)NN * CAP * sizeof(int);   //  8 MB
    int*   cnt    = (int*)ws;  ws += (size_t)NN * sizeof(int);
    float* bufA   = (float*)ws; ws += (size_t)NN * DD * sizeof(float);
    float* bufB   = (float*)ws;

    // workspace is poisoned each iteration: counters must start at zero
    hipMemsetAsync(cnt, 0, (size_t)NN * sizeof(int), stream);

    detect_kernel<<<DET_BLOCKS, 256, 0, stream>>>(A, cnt, colbuf);
    l1_kernel<<<NN, 256, 0, stream>>>(lw, x, W0, b0, cnt, colbuf, pairs, bufA);
    layer_kernel<<<NN / 4, 256, 0, stream>>>(bufA, pairs, cnt, W1, b1, bufB);
    layer_kernel<<<NN / 4, 256, 0, stream>>>(bufB, pairs, cnt, W2, b2, out);
}